// Round 1
// baseline (447.045 us; speedup 1.0000x reference)
//
#include <hip/hip_runtime.h>
#include <hip/hip_bf16.h>

// Shapes (fixed by the problem)
#define BATCH 256
#define F_DIM 2048
#define H_DIM 512
#define HH    256
#define NCLS  512
#define E_DIM 8

typedef __attribute__((ext_vector_type(8))) short  bf16x8;  // 8 bf16 = 4 VGPRs (MFMA A/B frag)
typedef __attribute__((ext_vector_type(4))) float  f32x4;   // MFMA C/D frag
typedef __attribute__((ext_vector_type(4))) unsigned short u16x4;

__device__ __forceinline__ unsigned short f2bf(float x) {
    union { float f; unsigned int u; } v; v.f = x;
    unsigned int r = v.u + 0x7fffu + ((v.u >> 16) & 1u);  // RNE
    return (unsigned short)(r >> 16);
}

// ---------------------------------------------------------------------------
// Kernel T: Ws [2048][512] fp32 -> WsT [512][2048] bf16 (k-contiguous rows)
// ---------------------------------------------------------------------------
__global__ __launch_bounds__(256) void k_transpose(
    const float* __restrict__ Ws, unsigned short* __restrict__ WsT)
{
    __shared__ float tile[64][68];  // stride 68 floats = 272 B (16B-aligned rows, no pow2 conflicts)
    const int bid = blockIdx.x;
    const int kt = bid & 31;        // 32 k-tiles of 64
    const int nt = bid >> 5;        // 8 n-tiles of 64
    const int k0 = kt * 64, n0 = nt * 64;
    const int tx = threadIdx.x & 15, ty = threadIdx.x >> 4;

#pragma unroll
    for (int i = 0; i < 4; ++i) {
        const int row = ty + i * 16;
        f32x4 v = *(const f32x4*)(Ws + (size_t)(k0 + row) * H_DIM + n0 + tx * 4);
        *(f32x4*)(&tile[row][tx * 4]) = v;
    }
    __syncthreads();
#pragma unroll
    for (int i = 0; i < 4; ++i) {
        const int n = ty + i * 16;
        u16x4 o;
#pragma unroll
        for (int j = 0; j < 4; ++j) o[j] = f2bf(tile[tx * 4 + j][n]);
        *(u16x4*)(WsT + (size_t)(n0 + n) * F_DIM + k0 + tx * 4) = o;
    }
}

// ---------------------------------------------------------------------------
// Kernel A: stage-1 GEMM partials. 512 wave-jobs = 16 m-tiles x 8 n-tiles x 4 k-splits.
// partials[kidx][256][512] fp32
// ---------------------------------------------------------------------------
__global__ __launch_bounds__(256) void k_gemm1(
    const float* __restrict__ features,        // [256][2048]
    const unsigned short* __restrict__ WsT,    // [512][2048] bf16
    float* __restrict__ partials)              // [4][256][512]
{
    const int tid = threadIdx.x;
    const int lane = tid & 63;
    const int wave = tid >> 6;
    const int job = blockIdx.x * 4 + wave;     // 0..511
    const int kidx = job & 3;
    const int nt = (job >> 2) & 7;
    const int mt = job >> 5;
    const int l15 = lane & 15, quad = lane >> 4;
    const int m0 = mt * 16, n0 = nt * 64, kb = kidx * 512;

    f32x4 z = {0.f, 0.f, 0.f, 0.f};
    f32x4 acc[4];
#pragma unroll
    for (int nf = 0; nf < 4; ++nf) acc[nf] = z;

    for (int ks = 0; ks < 16; ++ks) {
        const int kk = kb + ks * 32 + quad * 8;
        f32x4 a0 = *(const f32x4*)(features + (size_t)(m0 + l15) * F_DIM + kk);
        f32x4 a1 = *(const f32x4*)(features + (size_t)(m0 + l15) * F_DIM + kk + 4);
        bf16x8 aF;
#pragma unroll
        for (int j = 0; j < 4; ++j) { aF[j] = (short)f2bf(a0[j]); aF[4 + j] = (short)f2bf(a1[j]); }
#pragma unroll
        for (int nf = 0; nf < 4; ++nf) {
            bf16x8 bF = *(const bf16x8*)(WsT + (size_t)(n0 + nf * 16 + l15) * F_DIM + kk);
            acc[nf] = __builtin_amdgcn_mfma_f32_16x16x32_bf16(aF, bF, acc[nf], 0, 0, 0);
        }
    }
    // C/D layout: col = lane&15, row = quad*4 + reg
    float* po = partials + (size_t)kidx * (BATCH * H_DIM);
#pragma unroll
    for (int nf = 0; nf < 4; ++nf)
#pragma unroll
        for (int r = 0; r < 4; ++r)
            po[(size_t)(m0 + quad * 4 + r) * H_DIM + n0 + nf * 16 + l15] = acc[nf][r];
}

// ---------------------------------------------------------------------------
// Kernel A2: reduce 4 partials + bias + relu -> shared bf16 [256][512]
// ---------------------------------------------------------------------------
__global__ __launch_bounds__(256) void k_reduce_relu(
    const float* __restrict__ partials, const float* __restrict__ bs,
    unsigned short* __restrict__ sharedA)
{
    const int idx = (blockIdx.x * 256 + threadIdx.x) * 4;  // over 256*512 elems
    f32x4 s = *(const f32x4*)(partials + idx);
    s += *(const f32x4*)(partials + BATCH * H_DIM + idx);
    s += *(const f32x4*)(partials + 2 * BATCH * H_DIM + idx);
    s += *(const f32x4*)(partials + 3 * BATCH * H_DIM + idx);
    s += *(const f32x4*)(bs + (idx & (H_DIM - 1)));
    u16x4 o;
#pragma unroll
    for (int j = 0; j < 4; ++j) {
        float v = s[j] > 0.f ? s[j] : 0.f;
        o[j] = f2bf(v);
    }
    *(u16x4*)(sharedA + idx) = o;
}

// ---------------------------------------------------------------------------
// Kernel B (main): one block per class. h = relu(shared @ W1[c] + b1[c]);
// logits = h @ W2[c] + b2[c]; softmax -> out. W1[c] read exactly once.
// Two N-passes of 128 (acc = 128 VGPR/lane). BK=64 chunks, register-prefetch pipeline.
// ---------------------------------------------------------------------------
__global__ __launch_bounds__(256, 2) void k_main(
    const unsigned short* __restrict__ sharedA,  // [256][512] bf16
    const float* __restrict__ W1,                // [C][512][256]
    const float* __restrict__ b1,                // [C][256]
    const float* __restrict__ W2,                // [C][256][8]
    const float* __restrict__ b2,                // [C][8]
    float* __restrict__ out)                     // gate_weights [256][512][8], then gate_logits
{
    const int c = blockIdx.x;
    const int tid = threadIdx.x;
    const int lane = tid & 63;
    const int wave = tid >> 6;
    const int l15 = lane & 15;
    const int quad = lane >> 4;
    const int m0 = wave * 64;            // waves stacked in M (A-traffic minimal)
    const int nloc = tid & 127;
    const int half = tid >> 7;

    __shared__ unsigned short Blds[8 * 128 * 8];  // [kg][n][8] bf16, 16 KB
    __shared__ float w2s[128 * 8];                // pass slice of W2[c]
    __shared__ float b1s[128];
    __shared__ float logits_s[BATCH * E_DIM];     // 8 KB

    const float* W1c = W1 + (size_t)c * (H_DIM * HH);

    for (int pass = 0; pass < 2; ++pass) {
        const int n0p = pass * 128;
        // stage W2/b1 slices (consumed only in stage 3; barriers below cover visibility)
        {
            f32x4 w = *(const f32x4*)(W2 + (size_t)c * (HH * E_DIM) + n0p * E_DIM + tid * 4);
            *(f32x4*)(w2s + tid * 4) = w;
            if (tid < 128) b1s[tid] = b1[(size_t)c * HH + n0p + tid];
        }
        f32x4 z = {0.f, 0.f, 0.f, 0.f};
        f32x4 acc[4][8];
#pragma unroll
        for (int mf = 0; mf < 4; ++mf)
#pragma unroll
            for (int nf = 0; nf < 8; ++nf) acc[mf][nf] = z;

        // prefetch chunk 0: each thread a column-segment of 8 consecutive k at fixed n
        float rg[32];
#pragma unroll
        for (int i = 0; i < 4; ++i)
#pragma unroll
            for (int j = 0; j < 8; ++j)
                rg[i * 8 + j] = W1c[(size_t)((half + 2 * i) * 8 + j) * HH + n0p + nloc];

        for (int ch = 0; ch < 8; ++ch) {
            // convert + pack prefetched chunk into LDS ([kg][n][8] -> ds_write_b128)
#pragma unroll
            for (int i = 0; i < 4; ++i) {
                bf16x8 v;
#pragma unroll
                for (int j = 0; j < 8; ++j) v[j] = (short)rg[i * 8 + j] * 0 + (short)f2bf(rg[i * 8 + j]);
                *(bf16x8*)(&Blds[(((half + 2 * i) * 128 + nloc)) * 8]) = v;
            }
            __syncthreads();

            // issue next chunk's loads; they stay in flight across the compute
            float rn[32];
            if (ch < 7) {
#pragma unroll
                for (int i = 0; i < 4; ++i)
#pragma unroll
                    for (int j = 0; j < 8; ++j)
                        rn[i * 8 + j] = W1c[(size_t)((ch + 1) * 64 + (half + 2 * i) * 8 + j) * HH + n0p + nloc];
            }

            // compute: 2 k-steps of 32
#pragma unroll
            for (int ks = 0; ks < 2; ++ks) {
                const int kglob = ch * 64 + ks * 32 + quad * 8;
                bf16x8 aF[4];
#pragma unroll
                for (int mf = 0; mf < 4; ++mf)
                    aF[mf] = *(const bf16x8*)(sharedA + (size_t)(m0 + mf * 16 + l15) * H_DIM + kglob);
#pragma unroll
                for (int nf = 0; nf < 8; ++nf) {
                    bf16x8 bF = *(const bf16x8*)(&Blds[((ks * 4 + quad) * 128 + nf * 16 + l15) * 8]);
#pragma unroll
                    for (int mf = 0; mf < 4; ++mf)
                        acc[mf][nf] = __builtin_amdgcn_mfma_f32_16x16x32_bf16(aF[mf], bF, acc[mf][nf], 0, 0, 0);
                }
            }
            __syncthreads();
#pragma unroll
            for (int q = 0; q < 32; ++q) rg[q] = rn[q];
        }

        // ---- stage 3: partial logits for this pass's 128 columns ----
        // lane holds h for cols (nf*16 + l15), rows (m0 + mf*16 + quad*4 + r)
#pragma unroll
        for (int mf = 0; mf < 4; ++mf) {
            float part[4][E_DIM];
#pragma unroll
            for (int r = 0; r < 4; ++r)
#pragma unroll
                for (int e = 0; e < E_DIM; ++e) part[r][e] = 0.f;
#pragma unroll
            for (int nf = 0; nf < 8; ++nf) {
                const int col = nf * 16 + l15;
                f32x4 wA = *(const f32x4*)(w2s + col * 8);
                f32x4 wB = *(const f32x4*)(w2s + col * 8 + 4);
                const float bb = b1s[col];
#pragma unroll
                for (int r = 0; r < 4; ++r) {
                    float h = acc[mf][nf][r] + bb;
                    h = h > 0.f ? h : 0.f;
                    part[r][0] += h * wA[0]; part[r][1] += h * wA[1];
                    part[r][2] += h * wA[2]; part[r][3] += h * wA[3];
                    part[r][4] += h * wB[0]; part[r][5] += h * wB[1];
                    part[r][6] += h * wB[2]; part[r][7] += h * wB[3];
                }
            }
            // reduce across the 16 lanes of each quad (same rows, disjoint cols)
#pragma unroll
            for (int r = 0; r < 4; ++r)
#pragma unroll
                for (int e = 0; e < E_DIM; ++e) {
                    float v = part[r][e];
                    v += __shfl_xor(v, 1, 16);
                    v += __shfl_xor(v, 2, 16);
                    v += __shfl_xor(v, 4, 16);
                    v += __shfl_xor(v, 8, 16);
                    part[r][e] = v;
                }
            if (l15 == 0) {
#pragma unroll
                for (int r = 0; r < 4; ++r) {
                    const int row = m0 + mf * 16 + quad * 4 + r;
                    f32x4 lo = {part[r][0], part[r][1], part[r][2], part[r][3]};
                    f32x4 hi = {part[r][4], part[r][5], part[r][6], part[r][7]};
                    if (pass == 0) {
                        *(f32x4*)(logits_s + row * 8) = lo;
                        *(f32x4*)(logits_s + row * 8 + 4) = hi;
                    } else {
                        *(f32x4*)(logits_s + row * 8) = *(f32x4*)(logits_s + row * 8) + lo;
                        *(f32x4*)(logits_s + row * 8 + 4) = *(f32x4*)(logits_s + row * 8 + 4) + hi;
                    }
                }
            }
        }
        __syncthreads();
    }

    // ---- softmax epilogue: thread t handles batch row t ----
    f32x4 lg0 = *(f32x4*)(logits_s + tid * 8);
    f32x4 lg1 = *(f32x4*)(logits_s + tid * 8 + 4);
    lg0 += *(const f32x4*)(b2 + (size_t)c * E_DIM);
    lg1 += *(const f32x4*)(b2 + (size_t)c * E_DIM + 4);

    float lg[8] = {lg0[0], lg0[1], lg0[2], lg0[3], lg1[0], lg1[1], lg1[2], lg1[3]};
    float mx = lg[0];
#pragma unroll
    for (int e = 1; e < 8; ++e) mx = lg[e] > mx ? lg[e] : mx;
    float ex[8], s = 0.f;
#pragma unroll
    for (int e = 0; e < 8; ++e) { ex[e] = __expf(lg[e] - mx); s += ex[e]; }
    const float inv = 1.f / s;

    const size_t ob = ((size_t)tid * NCLS + c) * E_DIM;
    f32x4 w0 = {ex[0] * inv, ex[1] * inv, ex[2] * inv, ex[3] * inv};
    f32x4 w1 = {ex[4] * inv, ex[5] * inv, ex[6] * inv, ex[7] * inv};
    *(f32x4*)(out + ob) = w0;
    *(f32x4*)(out + ob + 4) = w1;
    const size_t lbase = (size_t)BATCH * NCLS * E_DIM;
    f32x4 o0 = {lg[0], lg[1], lg[2], lg[3]};
    f32x4 o1 = {lg[4], lg[5], lg[6], lg[7]};
    *(f32x4*)(out + lbase + ob) = o0;
    *(f32x4*)(out + lbase + ob + 4) = o1;
}

// ---------------------------------------------------------------------------
extern "C" void kernel_launch(void* const* d_in, const int* in_sizes, int n_in,
                              void* d_out, int out_size, void* d_ws, size_t ws_size,
                              hipStream_t stream) {
    const float* features = (const float*)d_in[0];  // [256][2048]
    const float* Ws       = (const float*)d_in[1];  // [2048][512]
    const float* bs       = (const float*)d_in[2];  // [512]
    const float* W1       = (const float*)d_in[3];  // [512][512][256]
    const float* b1       = (const float*)d_in[4];  // [512][256]
    const float* W2       = (const float*)d_in[5];  // [512][256][8]
    const float* b2       = (const float*)d_in[6];  // [512][8]
    float* out = (float*)d_out;

    char* ws = (char*)d_ws;
    unsigned short* WsT     = (unsigned short*)ws;                 // 512*2048*2   = 2 MB
    float*          parts   = (float*)(ws + 2097152);              // 4*256*512*4  = 2 MB
    unsigned short* sharedA = (unsigned short*)(ws + 4194304);     // 256*512*2    = 256 KB

    hipLaunchKernelGGL(k_transpose,   dim3(256), dim3(256), 0, stream, Ws, WsT);
    hipLaunchKernelGGL(k_gemm1,       dim3(128), dim3(256), 0, stream, features, WsT, parts);
    hipLaunchKernelGGL(k_reduce_relu, dim3(128), dim3(256), 0, stream, parts, bs, sharedA);
    hipLaunchKernelGGL(k_main,        dim3(NCLS), dim3(256), 0, stream, sharedA, W1, b1, W2, b2, out);
}